// Round 12
// baseline (33.492 us; speedup 1.0000x reference)
//
#include <hip/hip_runtime.h>
#include <math.h>

// Problem constants
constexpr int Bb = 8, Cc = 16, Hh = 96, Ww = 96;
constexpr int Ho = 94, Wo = 94;          // VALID 3x3
constexpr int NC = 4;                    // n_convs
constexpr int PLANE = Ho * Wo;           // 8836
constexpr int NPLANES = Bb * Cc;         // 128
constexpr int PPX = Hh * Ww;             // 9216 pixels per plane

constexpr int FS   = 12;                 // ushorts per record: b0..b7, silu, 0,0,0
constexpr int RECB = FS * 2;             // 24 B per record
constexpr int ROWB = Ww * RECB;          // 2304 B per plane row of records
constexpr size_t PLB = (size_t)PPX * RECB; // 221184 B per plane
constexpr int BWS  = 72;                 // Bw LDS row stride (ushorts)

// Kernel B tiling: (plane, ychunk, xt) blocks; 4 waves/block; 6 out-rows/wave.
constexpr int NXT = 6;                   // x strips of 16
constexpr int NYC = 4;                   // y chunks of 24 out-rows (last = 22)

typedef __attribute__((ext_vector_type(4))) float f32x4;
typedef __attribute__((ext_vector_type(8))) short bf16x8;

template <int N> struct IC { static constexpr int value = N; };

__device__ __forceinline__ unsigned short f2bf(float f) {
    union { float f; unsigned u; } a; a.f = f;
    unsigned r = a.u + 0x7fffu + ((a.u >> 16) & 1u);   // RNE
    return (unsigned short)(r >> 16);
}
__device__ __forceinline__ unsigned pk2(float a, float b) {
    return (unsigned)f2bf(a) | ((unsigned)f2bf(b) << 16);
}
__device__ __forceinline__ bf16x8 mkfrag(unsigned a0, unsigned a1, unsigned a2, unsigned a3) {
    union { unsigned u[4]; bf16x8 v; } t;
    t.u[0] = a0; t.u[1] = a1; t.u[2] = a2; t.u[3] = a3;
    return t.v;
}
// lane i <- lane i-4 / i-8 within each 16-lane row (row_shr, verified R10)
__device__ __forceinline__ float dpp_shr4(float v) {
    return __int_as_float(__builtin_amdgcn_update_dpp(0, __float_as_int(v), 0x114, 0xF, 0xF, true));
}
__device__ __forceinline__ float dpp_shr8(float v) {
    return __int_as_float(__builtin_amdgcn_update_dpp(0, __float_as_int(v), 0x118, 0xF, 0xF, true));
}

struct F4 { float v0, v1, v2, v3; } __attribute__((packed, aligned(4)));

// ================= Kernel A: per-pixel features -> ws (bf16 records) =================
__global__ __launch_bounds__(256)
void kan_feat_kernel(const float* __restrict__ x,
                     const float* __restrict__ grid,
                     unsigned short* __restrict__ ws)
{
    const int idx = blockIdx.x * 256 + threadIdx.x;    // < 128*9216 = 1179648 exact
    const float g0   = grid[0];
    const float invh = 1.0f / (grid[1] - g0);

    const float v = x[idx];                            // fully coalesced

    const float sl = v / (1.0f + __expf(-v));          // silu

    const float u = (v - g0) * invh;
    int j = (int)u;
    if (!(u >= 0.0f && u < 11.0f)) j = -100;           // outside grid -> all bases zero
    const float t  = u - (float)j;
    const float t2 = t * t, t3 = t2 * t;
    const float omt = 1.0f - t;
    const float B0 = (1.0f / 6.0f) * omt * omt * omt;
    const float B1 = (1.0f / 6.0f) * (3.0f * t3 - 6.0f * t2 + 4.0f);
    const float B2 = (1.0f / 6.0f) * (-3.0f * t3 + 3.0f * t2 + 3.0f * t + 1.0f);
    const float B3 = (1.0f / 6.0f) * t3;

    float bb[8];
#pragma unroll
    for (int k = 0; k < 8; ++k) {
        float r = 0.0f;
        r = (j == k + 3) ? B0 : r;
        r = (j == k + 2) ? B1 : r;
        r = (j == k + 1) ? B2 : r;
        r = (j == k    ) ? B3 : r;
        bb[k] = r;
    }

    unsigned short* fp = ws + (size_t)idx * FS;
    *reinterpret_cast<uint2*>(fp + 0) = make_uint2(pk2(bb[0], bb[1]), pk2(bb[2], bb[3]));
    *reinterpret_cast<uint2*>(fp + 4) = make_uint2(pk2(bb[4], bb[5]), pk2(bb[6], bb[7]));
    *reinterpret_cast<uint2*>(fp + 8) = make_uint2(pk2(sl, 0.0f), 0u);
}

// ================= Kernel B: sliding-dy MFMA conv from ws =================
__global__ __launch_bounds__(256)
void kan_conv_kernel(const unsigned short* __restrict__ ws,
                     const float* __restrict__ base_w,        // (4,9)
                     const float* __restrict__ spline_w,      // (4,9,8)
                     const float* __restrict__ spline_scaler, // (4,9)
                     float* __restrict__ out)                 // (8,64,94,94)
{
    __shared__ unsigned short Bw[16 * BWS];    // 2304 B merged weights [col=4d+cv][k]

    const int tid = threadIdx.x;
    int blk = blockIdx.x;
    const int xt    = blk % NXT; blk /= NXT;
    const int chunk = blk % NYC; blk /= NYC;
    const int plane = blk;                     // 0..127
    const int ox0 = xt * 16;
    const int c0  = chunk * 24;

    // ---------- Phase 0: merged d-packed weights -> LDS (verified R10 code) ----------
    {
        const int col = tid >> 4;         // 0..15 = 4*d + cv (12 used)
        const int k0  = (tid & 15) * 4;   // k 0..63
        const int d = col >> 2, cv = col & 3;
        unsigned short w[4];
#pragma unroll
        for (int e = 0; e < 4; ++e) {
            const int k = k0 + e;
            float val = 0.f;
            if (col < 12 && k < 36) {
                const int j = k / 12, o = k - 12 * j;     // j=dx, o=feat
                const int wi = cv * 9 + 3 * d + j;
                if (o < 8)       val = spline_scaler[wi] * spline_w[wi * 8 + o];
                else if (o == 8) val = base_w[wi];
            }
            w[e] = f2bf(val);
        }
        *reinterpret_cast<uint2*>(&Bw[col * BWS + k0]) =
            make_uint2((unsigned)w[0] | ((unsigned)w[1] << 16),
                       (unsigned)w[2] | ((unsigned)w[3] << 16));
    }
    __syncthreads();

    // ---------- Sliding MFMA: wave wv -> out rows c0+6wv .. +5 ----------
    const int lane = tid & 63;
    const int wv   = tid >> 6;
    const int r    = lane & 15;      // A row (window index) / B col (4d+cv)
    const int g    = lane >> 4;      // k-group

    const bf16x8 wb1 = *reinterpret_cast<const bf16x8*>(&Bw[r * BWS +  0 + 8 * g]);
    const bf16x8 wb2 = *reinterpret_cast<const bf16x8*>(&Bw[r * BWS + 32 + 8 * g]);

    const int ry = c0 + 6 * wv;      // first input row of this wave's window

    // Window for A row r starts at pixel column ox0+r (BUGFIX vs R11: ox0 was missing).
    // Column clamp to 93 keeps edge windows in-bounds; affects only discarded D rows.
    const int colb = ((ox0 + r < 93) ? (ox0 + r) : 93) * RECB;
    const char* pbase  = (const char*)ws + plane * PLB + colb;
    const char* base   = pbase + 16 * g;               // lo/hi reads (k = 8g..8g+7)
    const char* basex  = pbase + ((g == 0) ? 64 : 0);  // x2 read (real only for g=0)

    const int cvl = r & 3;
    float* obase = out + ((size_t)(plane * NC) + cvl) * PLANE;   // used when r in [8,12)
    const bool storer = (r >= 8) && (r < 12);
    const int oxs = ox0 + 4 * g;
    const bool fullstore = (oxs + 3 < Wo);

    f32x4 sA, sB, sC;
    const f32x4 zz = {0.f, 0.f, 0.f, 0.f};
    sA = zz; sB = zz; sC = zz;

    auto kstep = [&](auto ITC, f32x4& cur, f32x4& p1, f32x4& p2) {
        constexpr int IT = decltype(ITC)::value;
        // Row clamp: rows > 95 only feed discarded outputs; keep reads in-bounds.
        const int rr = (ry + IT <= 95) ? (ry + IT) : 95;
        const size_t ro = (size_t)rr * ROWB;
        const uint2 lo = *reinterpret_cast<const uint2*>(base + ro);
        const uint2 hi = *reinterpret_cast<const uint2*>(base + ro + 8);
        const uint2 x2 = *reinterpret_cast<const uint2*>(basex + ro);
        cur = __builtin_amdgcn_mfma_f32_16x16x32_bf16(mkfrag(lo.x, lo.y, hi.x, hi.y), wb1, zz, 0, 0, 0);
        cur = __builtin_amdgcn_mfma_f32_16x16x32_bf16(mkfrag(x2.x, x2.y, x2.x, x2.y), wb2, cur, 0, 0, 0);
        if constexpr (IT >= 2) {
            const int oy = ry + IT - 2;
            if (oy < Ho) {                         // wave-uniform
                f32x4 tot;
                // col 8+cv (d=2, cur) + col 4+cv (d=1, prev) + col cv (d=0, prev2)
                tot[0] = cur[0] + dpp_shr4(p1[0]) + dpp_shr8(p2[0]);
                tot[1] = cur[1] + dpp_shr4(p1[1]) + dpp_shr8(p2[1]);
                tot[2] = cur[2] + dpp_shr4(p1[2]) + dpp_shr8(p2[2]);
                tot[3] = cur[3] + dpp_shr4(p1[3]) + dpp_shr8(p2[3]);
                if (storer) {
                    float* op = obase + oy * Wo + oxs;
                    if (fullstore) {
                        F4 s; s.v0 = tot[0]; s.v1 = tot[1]; s.v2 = tot[2]; s.v3 = tot[3];
                        *reinterpret_cast<F4*>(op) = s;
                    } else {
#pragma unroll
                        for (int e = 0; e < 4; ++e)
                            if (oxs + e < Wo) op[e] = tot[e];
                    }
                }
            }
        }
    };

    kstep(IC<0>{}, sA, sC, sB);
    kstep(IC<1>{}, sB, sA, sC);
    kstep(IC<2>{}, sC, sB, sA);
    kstep(IC<3>{}, sA, sC, sB);
    kstep(IC<4>{}, sB, sA, sC);
    kstep(IC<5>{}, sC, sB, sA);
    kstep(IC<6>{}, sA, sC, sB);
    kstep(IC<7>{}, sB, sA, sC);
}

extern "C" void kernel_launch(void* const* d_in, const int* in_sizes, int n_in,
                              void* d_out, int out_size, void* d_ws, size_t ws_size,
                              hipStream_t stream) {
    const float* x             = (const float*)d_in[0];
    const float* base_w        = (const float*)d_in[1];
    const float* spline_w      = (const float*)d_in[2];
    const float* spline_scaler = (const float*)d_in[3];
    const float* grid          = (const float*)d_in[4];
    float* out = (float*)d_out;
    unsigned short* feat_ws = (unsigned short*)d_ws;   // 28.3 MB used

    // Kernel A: 1179648 pixels, 1/thread
    const int ablocks = (NPLANES * PPX) / 256;         // 4608 exact
    kan_feat_kernel<<<ablocks, 256, 0, stream>>>(x, grid, feat_ws);

    // Kernel B: (plane, ychunk, xt) blocks
    const int bblocks = NPLANES * NYC * NXT;           // 3072
    kan_conv_kernel<<<bblocks, 256, 0, stream>>>(feat_ws, base_w, spline_w,
                                                 spline_scaler, out);
}

// Round 13
// 21.609 us; speedup vs baseline: 1.5499x; 1.5499x over previous
//
#include <hip/hip_runtime.h>
#include <math.h>

// Problem constants
constexpr int Bb = 8, Cc = 16, Hh = 96, Ww = 96;
constexpr int Ho = 94, Wo = 94;          // VALID 3x3
constexpr int NC = 4;                    // n_convs
constexpr int PLANE = Ho * Wo;           // 8836

// Wave-autonomous tiling: each wave = 16 out-cols x 6 out-rows, from 18x8 inputs.
// Block = 4 waves (stacked in y: 24 out rows). Grid: 128 planes x 4 chunks x 6 xstrips.
constexpr int NXT = 6, NYC = 4;
constexpr int FS = 12;                   // ushorts per record: b0..b7, silu, 0,0,0
constexpr int WROWU = 18 * FS;           // 216 ushorts per buffer row
constexpr int WROWB = WROWU * 2;         // 432 B
constexpr int BWS = 72;                  // Bw LDS row stride (ushorts)

typedef __attribute__((ext_vector_type(4))) float f32x4;
typedef __attribute__((ext_vector_type(8))) short bf16x8;

template <int N> struct IC { static constexpr int value = N; };

__device__ __forceinline__ unsigned short f2bf(float f) {
    union { float f; unsigned u; } a; a.f = f;
    unsigned r = a.u + 0x7fffu + ((a.u >> 16) & 1u);   // RNE
    return (unsigned short)(r >> 16);
}
__device__ __forceinline__ unsigned pk2(float a, float b) {
    return (unsigned)f2bf(a) | ((unsigned)f2bf(b) << 16);
}
__device__ __forceinline__ bf16x8 mkfrag(unsigned a0, unsigned a1, unsigned a2, unsigned a3) {
    union { unsigned u[4]; bf16x8 v; } t;
    t.u[0] = a0; t.u[1] = a1; t.u[2] = a2; t.u[3] = a3;
    return t.v;
}
// lane i <- lane i-4 / i-8 within each 16-lane row (row_shr, verified R10)
__device__ __forceinline__ float dpp_shr4(float v) {
    return __int_as_float(__builtin_amdgcn_update_dpp(0, __float_as_int(v), 0x114, 0xF, 0xF, true));
}
__device__ __forceinline__ float dpp_shr8(float v) {
    return __int_as_float(__builtin_amdgcn_update_dpp(0, __float_as_int(v), 0x118, 0xF, 0xF, true));
}

struct F4 { float v0, v1, v2, v3; } __attribute__((packed, aligned(4)));

__global__ __launch_bounds__(256, 6)
void kan_fused_kernel(const float* __restrict__ x,
                      const float* __restrict__ base_w,        // (4,9)
                      const float* __restrict__ spline_w,      // (4,9,8)
                      const float* __restrict__ spline_scaler, // (4,9)
                      const float* __restrict__ grid,          // (12)
                      float* __restrict__ out)                 // (8,64,94,94)
{
    __shared__ unsigned short Bw[16 * BWS];        // 2304 B merged weights
    __shared__ unsigned short feat[4][8 * WROWU];  // 4 x 3456 B wave-private buffers

    const int tid = threadIdx.x;
    int blk = blockIdx.x;
    const int xt    = blk % NXT; blk /= NXT;
    const int chunk = blk % NYC; blk /= NYC;
    const int plane = blk;                     // 0..127
    const int ox0 = xt * 16;

    // ---------- Phase 0: merged d-packed weights -> LDS (R10-verified) ----------
    {
        const int col = tid >> 4;         // 0..15 = 4*d + cv (12 used)
        const int k0  = (tid & 15) * 4;   // k 0..63
        const int d = col >> 2, cv = col & 3;
        unsigned short w[4];
#pragma unroll
        for (int e = 0; e < 4; ++e) {
            const int k = k0 + e;
            float val = 0.f;
            if (col < 12 && k < 36) {
                const int j = k / 12, o = k - 12 * j;     // j=dx, o=feat
                const int wi = cv * 9 + 3 * d + j;
                if (o < 8)       val = spline_scaler[wi] * spline_w[wi * 8 + o];
                else if (o == 8) val = base_w[wi];
            }
            w[e] = f2bf(val);
        }
        *reinterpret_cast<uint2*>(&Bw[col * BWS + k0]) =
            make_uint2((unsigned)w[0] | ((unsigned)w[1] << 16),
                       (unsigned)w[2] | ((unsigned)w[3] << 16));
    }
    __syncthreads();   // the ONLY block barrier; covers tiny phase 0 only

    const int lane = tid & 63;
    const int wv   = tid >> 6;
    const int r    = lane & 15;      // A row (window) / B col (4d+cv)
    const int g    = lane >> 4;      // k-group

    const bf16x8 wb1 = *reinterpret_cast<const bf16x8*>(&Bw[r * BWS +  0 + 8 * g]);
    const bf16x8 wb2 = *reinterpret_cast<const bf16x8*>(&Bw[r * BWS + 32 + 8 * g]);

    const int ry = chunk * 24 + 6 * wv;      // first input row of this wave's window

    // ---------- Per-wave features: 144 records (8 rows x 18 cols) -> private LDS ----------
    const float g0   = grid[0];
    const float invh = 1.0f / (grid[1] - g0);
    const float* xplane = x + (size_t)plane * Hh * Ww;
    unsigned short* wbuf = &feat[wv][0];

#pragma unroll
    for (int q = 0; q < 3; ++q) {
        const int p = lane + 64 * q;         // record index 0..143
        if (p < 144) {                       // only q=2 partially active
            const int row = p / 18, col = p - 18 * row;
            const int gy = (ry + row <= 95) ? (ry + row) : 95;   // clamped rows feed discarded outputs
            const int gx = ox0 + col;
            const float v = (gx < Ww) ? xplane[gy * Ww + gx] : 0.0f;

            const float sl = v / (1.0f + __expf(-v));   // silu

            const float u = (v - g0) * invh;
            int j = (int)u;
            if (!(u >= 0.0f && u < 11.0f)) j = -100;
            const float t  = u - (float)j;
            const float t2 = t * t, t3 = t2 * t;
            const float omt = 1.0f - t;
            const float B0 = (1.0f / 6.0f) * omt * omt * omt;
            const float B1 = (1.0f / 6.0f) * (3.0f * t3 - 6.0f * t2 + 4.0f);
            const float B2 = (1.0f / 6.0f) * (-3.0f * t3 + 3.0f * t2 + 3.0f * t + 1.0f);
            const float B3 = (1.0f / 6.0f) * t3;

            float bb[8];
#pragma unroll
            for (int k = 0; k < 8; ++k) {
                float rr = 0.0f;
                rr = (j == k + 3) ? B0 : rr;
                rr = (j == k + 2) ? B1 : rr;
                rr = (j == k + 1) ? B2 : rr;
                rr = (j == k    ) ? B3 : rr;
                bb[k] = rr;
            }

            unsigned short* fp = wbuf + p * FS;
            *reinterpret_cast<uint2*>(fp + 0) = make_uint2(pk2(bb[0], bb[1]), pk2(bb[2], bb[3]));
            *reinterpret_cast<uint2*>(fp + 4) = make_uint2(pk2(bb[4], bb[5]), pk2(bb[6], bb[7]));
            *reinterpret_cast<uint2*>(fp + 8) = make_uint2(pk2(sl, 0.0f), 0u);
        }
    }
    // Same-wave LDS RAW: compiler inserts lgkmcnt waits (no barrier needed).

    // ---------- Sliding-dy MFMA over the private buffer (R12-verified kstep) ----------
    const char* base  = (const char*)wbuf + 24 * r + 16 * g;
    const char* basex = (const char*)wbuf + 24 * r + ((g == 0) ? 64 : 0);

    const int cvl = r & 3;
    float* obase = out + ((size_t)(plane * NC) + cvl) * PLANE;   // used when r in [8,12)
    const bool storer = (r >= 8) && (r < 12);
    const int oxs = ox0 + 4 * g;
    const bool fullstore = (oxs + 3 < Wo);

    f32x4 sA, sB, sC;
    const f32x4 zz = {0.f, 0.f, 0.f, 0.f};
    sA = zz; sB = zz; sC = zz;

    auto kstep = [&](auto ITC, f32x4& cur, f32x4& p1, f32x4& p2) {
        constexpr int IT = decltype(ITC)::value;
        const int ro = IT * WROWB;
        const uint2 lo = *reinterpret_cast<const uint2*>(base + ro);
        const uint2 hi = *reinterpret_cast<const uint2*>(base + ro + 8);
        const uint2 x2 = *reinterpret_cast<const uint2*>(basex + ro);
        cur = __builtin_amdgcn_mfma_f32_16x16x32_bf16(mkfrag(lo.x, lo.y, hi.x, hi.y), wb1, zz, 0, 0, 0);
        cur = __builtin_amdgcn_mfma_f32_16x16x32_bf16(mkfrag(x2.x, x2.y, x2.x, x2.y), wb2, cur, 0, 0, 0);
        if constexpr (IT >= 2) {
            const int oy = ry + IT - 2;
            if (oy < Ho) {                         // wave-uniform
                f32x4 tot;
                // col 8+cv (d=2, cur) + col 4+cv (d=1, prev) + col cv (d=0, prev2)
                tot[0] = cur[0] + dpp_shr4(p1[0]) + dpp_shr8(p2[0]);
                tot[1] = cur[1] + dpp_shr4(p1[1]) + dpp_shr8(p2[1]);
                tot[2] = cur[2] + dpp_shr4(p1[2]) + dpp_shr8(p2[2]);
                tot[3] = cur[3] + dpp_shr4(p1[3]) + dpp_shr8(p2[3]);
                if (storer) {
                    float* op = obase + oy * Wo + oxs;
                    if (fullstore) {
                        F4 s; s.v0 = tot[0]; s.v1 = tot[1]; s.v2 = tot[2]; s.v3 = tot[3];
                        *reinterpret_cast<F4*>(op) = s;
                    } else {
#pragma unroll
                        for (int e = 0; e < 4; ++e)
                            if (oxs + e < Wo) op[e] = tot[e];
                    }
                }
            }
        }
    };

    kstep(IC<0>{}, sA, sC, sB);
    kstep(IC<1>{}, sB, sA, sC);
    kstep(IC<2>{}, sC, sB, sA);
    kstep(IC<3>{}, sA, sC, sB);
    kstep(IC<4>{}, sB, sA, sC);
    kstep(IC<5>{}, sC, sB, sA);
    kstep(IC<6>{}, sA, sC, sB);
    kstep(IC<7>{}, sB, sA, sC);
}

extern "C" void kernel_launch(void* const* d_in, const int* in_sizes, int n_in,
                              void* d_out, int out_size, void* d_ws, size_t ws_size,
                              hipStream_t stream) {
    const float* x             = (const float*)d_in[0];
    const float* base_w        = (const float*)d_in[1];
    const float* spline_w      = (const float*)d_in[2];
    const float* spline_scaler = (const float*)d_in[3];
    const float* grid          = (const float*)d_in[4];
    float* out = (float*)d_out;

    const int nblocks = (Bb * Cc) * NYC * NXT;  // 128*4*6 = 3072
    kan_fused_kernel<<<nblocks, 256, 0, stream>>>(x, base_w, spline_w,
                                                  spline_scaler, grid, out);
}

// Round 14
// 19.219 us; speedup vs baseline: 1.7427x; 1.1244x over previous
//
#include <hip/hip_runtime.h>
#include <math.h>

// Problem constants
constexpr int Bb = 8, Cc = 16, Hh = 96, Ww = 96;
constexpr int Ho = 94, Wo = 94;          // VALID 3x3
constexpr int NC = 4;                    // n_convs
constexpr int PLANE = Ho * Wo;           // 8836

// Wave-autonomous tiling: each wave = 16 out-cols x 12 out-rows, from 18x14 inputs.
// Block = 4 waves (48 out rows). Grid: 128 planes x 2 chunks x 6 xstrips = 1536 = 6/CU.
constexpr int NXT = 6, NYC = 2;
constexpr int FS = 12;                   // ushorts per record: b0..b7, silu, 0,0,0
constexpr int WROWU = 18 * FS;           // 216 ushorts per buffer row
constexpr int WROWB = WROWU * 2;         // 432 B
constexpr int IN_ROWS = 14;              // input rows per wave (12 out + 2 halo)
constexpr int NREC = IN_ROWS * 18;       // 252 records per wave
constexpr int BWS = 72;                  // Bw LDS row stride (ushorts)

typedef __attribute__((ext_vector_type(4))) float f32x4;
typedef __attribute__((ext_vector_type(8))) short bf16x8;

template <int N> struct IC { static constexpr int value = N; };

__device__ __forceinline__ unsigned short f2bf(float f) {
    union { float f; unsigned u; } a; a.f = f;
    unsigned r = a.u + 0x7fffu + ((a.u >> 16) & 1u);   // RNE
    return (unsigned short)(r >> 16);
}
__device__ __forceinline__ unsigned pk2(float a, float b) {
    return (unsigned)f2bf(a) | ((unsigned)f2bf(b) << 16);
}
__device__ __forceinline__ bf16x8 mkfrag(unsigned a0, unsigned a1, unsigned a2, unsigned a3) {
    union { unsigned u[4]; bf16x8 v; } t;
    t.u[0] = a0; t.u[1] = a1; t.u[2] = a2; t.u[3] = a3;
    return t.v;
}
// lane i <- lane i-4 / i-8 within each 16-lane row (row_shr, verified R10)
__device__ __forceinline__ float dpp_shr4(float v) {
    return __int_as_float(__builtin_amdgcn_update_dpp(0, __float_as_int(v), 0x114, 0xF, 0xF, true));
}
__device__ __forceinline__ float dpp_shr8(float v) {
    return __int_as_float(__builtin_amdgcn_update_dpp(0, __float_as_int(v), 0x118, 0xF, 0xF, true));
}

struct F4 { float v0, v1, v2, v3; } __attribute__((packed, aligned(4)));

__global__ __launch_bounds__(256, 6)
void kan_fused_kernel(const float* __restrict__ x,
                      const float* __restrict__ base_w,        // (4,9)
                      const float* __restrict__ spline_w,      // (4,9,8)
                      const float* __restrict__ spline_scaler, // (4,9)
                      const float* __restrict__ grid,          // (12)
                      float* __restrict__ out)                 // (8,64,94,94)
{
    __shared__ unsigned short Bw[16 * BWS];              // 2304 B merged weights
    __shared__ unsigned short feat[4][IN_ROWS * WROWU];  // 4 x 6048 B wave-private

    const int tid = threadIdx.x;
    int blk = blockIdx.x;
    const int xt    = blk % NXT; blk /= NXT;
    const int chunk = blk % NYC; blk /= NYC;
    const int plane = blk;                     // 0..127
    const int ox0 = xt * 16;

    // ---------- Phase 0: merged d-packed weights -> LDS (R10-verified) ----------
    {
        const int col = tid >> 4;         // 0..15 = 4*d + cv (12 used)
        const int k0  = (tid & 15) * 4;   // k 0..63
        const int d = col >> 2, cv = col & 3;
        unsigned short w[4];
#pragma unroll
        for (int e = 0; e < 4; ++e) {
            const int k = k0 + e;
            float val = 0.f;
            if (col < 12 && k < 36) {
                const int j = k / 12, o = k - 12 * j;     // j=dx, o=feat
                const int wi = cv * 9 + 3 * d + j;
                if (o < 8)       val = spline_scaler[wi] * spline_w[wi * 8 + o];
                else if (o == 8) val = base_w[wi];
            }
            w[e] = f2bf(val);
        }
        *reinterpret_cast<uint2*>(&Bw[col * BWS + k0]) =
            make_uint2((unsigned)w[0] | ((unsigned)w[1] << 16),
                       (unsigned)w[2] | ((unsigned)w[3] << 16));
    }
    __syncthreads();   // the ONLY block barrier; covers tiny phase 0 only

    const int lane = tid & 63;
    const int wv   = tid >> 6;
    const int r    = lane & 15;      // A row (window) / B col (4d+cv)
    const int g    = lane >> 4;      // k-group

    const bf16x8 wb1 = *reinterpret_cast<const bf16x8*>(&Bw[r * BWS +  0 + 8 * g]);
    const bf16x8 wb2 = *reinterpret_cast<const bf16x8*>(&Bw[r * BWS + 32 + 8 * g]);

    const int ry = chunk * 48 + 12 * wv;     // first input row of this wave's window

    // ---------- Per-wave features: 252 records (14 rows x 18 cols) -> private LDS ----------
    const float g0   = grid[0];
    const float invh = 1.0f / (grid[1] - g0);
    const float* xplane = x + (size_t)plane * Hh * Ww;
    unsigned short* wbuf = &feat[wv][0];

    // Load phase: issue all 4 independent global loads first (latency overlap).
    float vv0 = 0.f, vv1 = 0.f, vv2 = 0.f, vv3 = 0.f;
#pragma unroll
    for (int q = 0; q < 4; ++q) {
        const int p = lane + 64 * q;         // record index
        if (p < NREC) {                      // q=3: lanes 0..59 only
            const int row = p / 18, col = p - 18 * row;
            const int gy = (ry + row <= 95) ? (ry + row) : 95;   // clamp -> discarded outputs
            const int gxr = ox0 + col;
            const int gx = (gxr <= 95) ? gxr : 95;               // clamp -> discarded outputs
            const float v = xplane[gy * Ww + gx];
            if      (q == 0) vv0 = v;
            else if (q == 1) vv1 = v;
            else if (q == 2) vv2 = v;
            else             vv3 = v;
        }
    }

    // Compute phase: spline + silu chains, ds_write.
#pragma unroll
    for (int q = 0; q < 4; ++q) {
        const int p = lane + 64 * q;
        if (p < NREC) {
            const float v = (q == 0) ? vv0 : (q == 1) ? vv1 : (q == 2) ? vv2 : vv3;

            const float sl = v / (1.0f + __expf(-v));   // silu

            const float u = (v - g0) * invh;
            int j = (int)u;
            if (!(u >= 0.0f && u < 11.0f)) j = -100;
            const float t  = u - (float)j;
            const float t2 = t * t, t3 = t2 * t;
            const float omt = 1.0f - t;
            const float B0 = (1.0f / 6.0f) * omt * omt * omt;
            const float B1 = (1.0f / 6.0f) * (3.0f * t3 - 6.0f * t2 + 4.0f);
            const float B2 = (1.0f / 6.0f) * (-3.0f * t3 + 3.0f * t2 + 3.0f * t + 1.0f);
            const float B3 = (1.0f / 6.0f) * t3;

            float bb[8];
#pragma unroll
            for (int k = 0; k < 8; ++k) {
                float rr = 0.0f;
                rr = (j == k + 3) ? B0 : rr;
                rr = (j == k + 2) ? B1 : rr;
                rr = (j == k + 1) ? B2 : rr;
                rr = (j == k    ) ? B3 : rr;
                bb[k] = rr;
            }

            unsigned short* fp = wbuf + p * FS;
            *reinterpret_cast<uint2*>(fp + 0) = make_uint2(pk2(bb[0], bb[1]), pk2(bb[2], bb[3]));
            *reinterpret_cast<uint2*>(fp + 4) = make_uint2(pk2(bb[4], bb[5]), pk2(bb[6], bb[7]));
            *reinterpret_cast<uint2*>(fp + 8) = make_uint2(pk2(sl, 0.0f), 0u);
        }
    }
    // Same-wave LDS RAW: compiler inserts lgkmcnt waits (no barrier needed).

    // ---------- Sliding-dy MFMA over the private buffer (R12/R13-verified kstep) ----------
    const char* base  = (const char*)wbuf + 24 * r + 16 * g;
    const char* basex = (const char*)wbuf + 24 * r + ((g == 0) ? 64 : 0);

    const int cvl = r & 3;
    float* obase = out + ((size_t)(plane * NC) + cvl) * PLANE;   // used when r in [8,12)
    const bool storer = (r >= 8) && (r < 12);
    const int oxs = ox0 + 4 * g;
    const bool fullstore = (oxs + 3 < Wo);

    f32x4 sA, sB, sC;
    const f32x4 zz = {0.f, 0.f, 0.f, 0.f};
    sA = zz; sB = zz; sC = zz;

    auto kstep = [&](auto ITC, f32x4& cur, f32x4& p1, f32x4& p2) {
        constexpr int IT = decltype(ITC)::value;
        const int ro = IT * WROWB;
        const uint2 lo = *reinterpret_cast<const uint2*>(base + ro);
        const uint2 hi = *reinterpret_cast<const uint2*>(base + ro + 8);
        const uint2 x2 = *reinterpret_cast<const uint2*>(basex + ro);
        cur = __builtin_amdgcn_mfma_f32_16x16x32_bf16(mkfrag(lo.x, lo.y, hi.x, hi.y), wb1, zz, 0, 0, 0);
        cur = __builtin_amdgcn_mfma_f32_16x16x32_bf16(mkfrag(x2.x, x2.y, x2.x, x2.y), wb2, cur, 0, 0, 0);
        if constexpr (IT >= 2) {
            const int oy = ry + IT - 2;
            if (oy < Ho) {                         // wave-uniform
                f32x4 tot;
                // col 8+cv (d=2, cur) + col 4+cv (d=1, prev) + col cv (d=0, prev2)
                tot[0] = cur[0] + dpp_shr4(p1[0]) + dpp_shr8(p2[0]);
                tot[1] = cur[1] + dpp_shr4(p1[1]) + dpp_shr8(p2[1]);
                tot[2] = cur[2] + dpp_shr4(p1[2]) + dpp_shr8(p2[2]);
                tot[3] = cur[3] + dpp_shr4(p1[3]) + dpp_shr8(p2[3]);
                if (storer) {
                    float* op = obase + oy * Wo + oxs;
                    if (fullstore) {
                        F4 s; s.v0 = tot[0]; s.v1 = tot[1]; s.v2 = tot[2]; s.v3 = tot[3];
                        *reinterpret_cast<F4*>(op) = s;
                    } else {
#pragma unroll
                        for (int e = 0; e < 4; ++e)
                            if (oxs + e < Wo) op[e] = tot[e];
                    }
                }
            }
        }
    };

    kstep(IC<0>{},  sA, sC, sB);
    kstep(IC<1>{},  sB, sA, sC);
    kstep(IC<2>{},  sC, sB, sA);
    kstep(IC<3>{},  sA, sC, sB);
    kstep(IC<4>{},  sB, sA, sC);
    kstep(IC<5>{},  sC, sB, sA);
    kstep(IC<6>{},  sA, sC, sB);
    kstep(IC<7>{},  sB, sA, sC);
    kstep(IC<8>{},  sC, sB, sA);
    kstep(IC<9>{},  sA, sC, sB);
    kstep(IC<10>{}, sB, sA, sC);
    kstep(IC<11>{}, sC, sB, sA);
    kstep(IC<12>{}, sA, sC, sB);
    kstep(IC<13>{}, sB, sA, sC);
}

extern "C" void kernel_launch(void* const* d_in, const int* in_sizes, int n_in,
                              void* d_out, int out_size, void* d_ws, size_t ws_size,
                              hipStream_t stream) {
    const float* x             = (const float*)d_in[0];
    const float* base_w        = (const float*)d_in[1];
    const float* spline_w      = (const float*)d_in[2];
    const float* spline_scaler = (const float*)d_in[3];
    const float* grid          = (const float*)d_in[4];
    float* out = (float*)d_out;

    const int nblocks = (Bb * Cc) * NYC * NXT;  // 128*2*6 = 1536 = 6/CU
    kan_fused_kernel<<<nblocks, 256, 0, stream>>>(x, base_w, spline_w,
                                                  spline_scaler, grid, out);
}